// Round 5
// baseline (636.536 us; speedup 1.0000x reference)
//
#include <hip/hip_runtime.h>
#include <cmath>
#include <cstdint>
#include <cstddef>

#define HDIM 2048
#define NEXP 64
#define HC   64                 // h per LDS chunk
#define NCH  (HDIM / HC)        // 32 chunks
#define BTOK 64                 // tokens per block
#define NBLK 256                // N / BTOK for N = 16384
#define LGP  68                 // logits-tile pitch

// ---------------------------------------------------------------------------
// W[64][2048] -> Wt[2048][64]  (coalesced write; reads are L2-served, 512 KB)
// ---------------------------------------------------------------------------
__global__ __launch_bounds__(256) void moe_wt(const float* __restrict__ W,
                                              float* __restrict__ Wt) {
  const int g = blockIdx.x * 256 + threadIdx.x;       // 0 .. 131071
  Wt[g] = W[(g & 63) * HDIM + (g >> 6)];
}

// ---------------------------------------------------------------------------
// Fused gate: GEMM (lane = token, 8 waves x 8 experts, full H) + softmax +
// top-2 + renorm + per-block loss partials. grid = N/64 blocks x 512 thr.
// x via XOR-swizzled LDS (1 b128 per 4h per wave); W via wave-uniform loads.
// ---------------------------------------------------------------------------
__global__ __launch_bounds__(512) void moe_fused(const float* __restrict__ x,
                                                 const float* __restrict__ Wt,
                                                 float* __restrict__ outS,
                                                 float* __restrict__ outI,
                                                 float* __restrict__ esumP,
                                                 float* __restrict__ lse2P) {
  __shared__ __align__(16) float xt[2][BTOK][HC];  // 32 KB, XOR-swizzled rows
  __shared__ __align__(16) float lg[BTOK][LGP];    // logits, later p-values
  __shared__ float invS[BTOK];
  __shared__ float lseL[BTOK];
  __shared__ float esL[8][NEXP];

  const int b    = blockIdx.x;
  const int tok0 = b * BTOK;
  const int tid  = threadIdx.x;
  const int t    = tid & 63;                                  // lane = token
  const int wu   = __builtin_amdgcn_readfirstlane(tid >> 6);  // wave id (SGPR)
  const int e0   = wu << 3;                                   // 8 experts/wave

  // staging map: thread -> (token st, quad sq and sq+8); coalesced 128B rows
  const int st  = tid >> 3;
  const int sq  = tid & 7;
  const float* xg = x + (size_t)(tok0 + st) * HDIM + (sq << 2);
  char* xtb = (char*)&xt[0][0][0];
  const int wb0 = st * 256 + ((sq ^ (st & 15)) << 4);         // swizzled dest
  const int wb1 = st * 256 + (((sq + 8) ^ (st & 15)) << 4);

  float acc[8];
#pragma unroll
  for (int e = 0; e < 8; ++e) acc[e] = 0.f;

  // prologue: stage chunk 0
  {
    const float4 v0 = *reinterpret_cast<const float4*>(xg);
    const float4 v1 = *reinterpret_cast<const float4*>(xg + 32);
    *reinterpret_cast<float4*>(xtb + wb0) = v0;
    *reinterpret_cast<float4*>(xtb + wb1) = v1;
  }
  __syncthreads();

  const int sw = (t & 15) << 4;   // read-side XOR (matches write side)
  int cur = 0;
  for (int c = 0; c < NCH; ++c) {
    float4 p0, p1;
    const bool more = (c + 1 < NCH);
    if (more) {   // issue next chunk's global loads; HBM latency hides under FMAs
      p0 = *reinterpret_cast<const float4*>(xg + (c + 1) * HC);
      p1 = *reinterpret_cast<const float4*>(xg + (c + 1) * HC + 32);
    }
    const char*  rb   = xtb + cur * (BTOK * HC * 4) + t * 256;
    const float* wrow = Wt + (c * HC) * NEXP + e0;            // wave-uniform
#pragma unroll
    for (int k = 0; k < 16; ++k) {                            // 4 h per quad
      const float4 xv = *reinterpret_cast<const float4*>(rb + ((k << 4) ^ sw));
      const float xs[4] = {xv.x, xv.y, xv.z, xv.w};
      const float* wp = wrow + (k << 2) * NEXP;
#pragma unroll
      for (int j = 0; j < 4; ++j) {
        const float4 wa = *reinterpret_cast<const float4*>(wp + j * NEXP);
        const float4 wb = *reinterpret_cast<const float4*>(wp + j * NEXP + 4);
        acc[0] = fmaf(xs[j], wa.x, acc[0]);
        acc[1] = fmaf(xs[j], wa.y, acc[1]);
        acc[2] = fmaf(xs[j], wa.z, acc[2]);
        acc[3] = fmaf(xs[j], wa.w, acc[3]);
        acc[4] = fmaf(xs[j], wb.x, acc[4]);
        acc[5] = fmaf(xs[j], wb.y, acc[5]);
        acc[6] = fmaf(xs[j], wb.z, acc[6]);
        acc[7] = fmaf(xs[j], wb.w, acc[7]);
      }
    }
    if (more) {
      char* nb = xtb + (cur ^ 1) * (BTOK * HC * 4);
      *reinterpret_cast<float4*>(nb + wb0) = p0;
      *reinterpret_cast<float4*>(nb + wb1) = p1;
    }
    __syncthreads();
    cur ^= 1;
  }

  // ---- logits -> lg tile (wave wu owns expert columns e0..e0+7) ----
  *reinterpret_cast<float4*>(&lg[t][e0])     = make_float4(acc[0], acc[1], acc[2], acc[3]);
  *reinterpret_cast<float4*>(&lg[t][e0 + 4]) = make_float4(acc[4], acc[5], acc[6], acc[7]);
  __syncthreads();

  // ---- gate: wave 0, lane = token, serial scan over 64 experts ----
  if (wu == 0) {
    float m = -INFINITY, l2v = -INFINITY;
    int i1 = 0, i2 = 0;
#pragma unroll
    for (int k = 0; k < 16; ++k) {
      const float4 lv = *reinterpret_cast<const float4*>(&lg[t][k << 2]);
      const float ls[4] = {lv.x, lv.y, lv.z, lv.w};
#pragma unroll
      for (int j = 0; j < 4; ++j) {
        const float l = ls[j];
        const int e = (k << 2) + j;
        if (l > m)        { l2v = m; i2 = i1; m = l; i1 = e; }
        else if (l > l2v) { l2v = l; i2 = e; }
      }
    }
    float s = 0.f;
#pragma unroll
    for (int k = 0; k < 16; ++k) {
      float4 lv = *reinterpret_cast<const float4*>(&lg[t][k << 2]);
      lv.x = expf(lv.x - m); s += lv.x;
      lv.y = expf(lv.y - m); s += lv.y;
      lv.z = expf(lv.z - m); s += lv.z;
      lv.w = expf(lv.w - m); s += lv.w;
      *reinterpret_cast<float4*>(&lg[t][k << 2]) = lv;   // store p-values
    }
    const float v1s = 1.f / s;                 // top-1 score
    const float v2s = expf(l2v - m) / s;       // top-2 score
    const float mx  = fmaxf(v1s, v2s);
    const float e1  = expf(v1s - mx), e2 = expf(v2s - mx);
    const float inv = 1.f / (e1 + e2);
    *reinterpret_cast<float2*>(&outS[2 * (size_t)(tok0 + t)]) = make_float2(e1 * inv, e2 * inv);
    *reinterpret_cast<float2*>(&outI[2 * (size_t)(tok0 + t)]) = make_float2((float)i1, (float)i2);
    invS[t] = v1s;
    const float lse = m + logf(s);
    lseL[t] = lse * lse;
  }
  __syncthreads();

  // ---- loss partials: lane = expert; wave wu sums its 8 tokens ----
  {
    float ea = 0.f;
#pragma unroll
    for (int i = 0; i < 8; ++i) {
      const int tt = (wu << 3) + i;
      ea = fmaf(lg[tt][t], invS[tt], ea);
    }
    esL[wu][t] = ea;
  }
  __syncthreads();
  if (wu == 0) {
    float tot = esL[0][t];
#pragma unroll
    for (int w2 = 1; w2 < 8; ++w2) tot += esL[w2][t];
    esumP[(size_t)t * NBLK + b] = tot;     // [e][block] layout
  }
  if (wu == 1) {
    float la = lseL[t];
#pragma unroll
    for (int d = 1; d < 64; d <<= 1) la += __shfl_xor(la, d);
    if (t == 0) lse2P[b] = la;
  }
}

// ---------------------------------------------------------------------------
// Loss finalize: 1 block x 256 threads, deterministic fixed-order reduction.
// ---------------------------------------------------------------------------
__global__ __launch_bounds__(256) void moe_loss(const float* __restrict__ esumP,
                                                const float* __restrict__ lse2P,
                                                float* __restrict__ outL, int N) {
  __shared__ float esF[NEXP];
  __shared__ float l4[4];
  const int tid = threadIdx.x, lane = tid & 63, w = tid >> 6;

  // expert sums: thread (e = tid>>2, q = tid&3) reads 64 contiguous floats
  const int e = tid >> 2, q = tid & 3;
  const float4* colp = reinterpret_cast<const float4*>(&esumP[(size_t)e * NBLK + q * 64]);
  float a = 0.f;
#pragma unroll
  for (int i = 0; i < 16; ++i) {
    const float4 t4 = colp[i];
    a += ((t4.x + t4.y) + t4.z) + t4.w;
  }
  a += __shfl_xor(a, 1);
  a += __shfl_xor(a, 2);
  if (q == 0) esF[e] = a;

  // lse^2 total (NBLK == 256 == blockDim)
  float la = lse2P[tid];
#pragma unroll
  for (int d = 1; d < 64; d <<= 1) la += __shfl_xor(la, d);
  if (lane == 0) l4[w] = la;
  __syncthreads();

  if (tid < NEXP) {
    const float load = esF[tid] / (float)N;
    const float dv   = load - 1.0f / 64.0f;
    float qq = dv * dv;
#pragma unroll
    for (int d = 1; d < 64; d <<= 1) qq += __shfl_xor(qq, d);
    if (tid == 0) {
      const float lseSum = ((l4[0] + l4[1]) + l4[2]) + l4[3];
      outL[0] = 0.01f * qq + 1e-4f * (lseSum / (float)N);
    }
  }
}

// ---------------------------------------------------------------------------
extern "C" void kernel_launch(void* const* d_in, const int* in_sizes, int n_in,
                              void* d_out, int out_size, void* d_ws, size_t ws_size,
                              hipStream_t stream) {
  const float* x = (const float*)d_in[0];
  const float* W = (const float*)d_in[1];
  const int N = in_sizes[0] / HDIM;   // 16384

  float* out  = (float*)d_out;
  float* outS = out;                  // [N,2]
  float* outI = out + (size_t)2 * N;  // [N,2]
  float* outL = out + (size_t)4 * N;  // scalar

  float* Wt    = (float*)d_ws;                       // [2048][64] = 512 KB
  float* esumP = Wt + (size_t)HDIM * NEXP;           // [64][NBLK]
  float* lse2P = esumP + (size_t)NEXP * NBLK;        // [NBLK]

  moe_wt<<<dim3((HDIM * NEXP) / 256), dim3(256), 0, stream>>>(W, Wt);
  moe_fused<<<dim3(N / BTOK), dim3(512), 0, stream>>>(x, Wt, outS, outI, esumP, lse2P);
  moe_loss<<<dim3(1), dim3(256), 0, stream>>>(esumP, lse2P, outL, N);
}